// Round 1
// baseline (606.760 us; speedup 1.0000x reference)
//
#include <hip/hip_runtime.h>
#include <cstdint>

#define B_ 16
#define H_ 224
#define W_ 224
#define C_ 32
#define HW_ (H_*W_)            // 50176
#define NTOT_ ((size_t)B_*HW_*C_)

__device__ __forceinline__ unsigned int enc_f32(float f) {
    unsigned int u = __float_as_uint(f);
    return (u & 0x80000000u) ? ~u : (u | 0x80000000u);
}
__device__ __forceinline__ float dec_f32(unsigned int u) {
    unsigned int v = (u & 0x80000000u) ? (u & 0x7fffffffu) : ~u;
    return __uint_as_float(v);
}

__global__ void k_init(unsigned int* scratch) {
    int t = threadIdx.x;
    if (t < B_) { scratch[t] = 0xFFFFFFFFu; scratch[B_ + t] = 0u; }
}

// K1: NHWC -> NCHW transpose (per-b 2D transpose of [HW][C]) + per-sample min/max
__global__ __launch_bounds__(256) void k_transpose_minmax(
        const float* __restrict__ x, float* __restrict__ xt,
        unsigned int* __restrict__ scratch) {
    __shared__ float tile[32][33];
    __shared__ float rmin[4], rmax[4];
    int b = blockIdx.y;
    int hw0 = blockIdx.x * 32;
    int lane = threadIdx.x & 31;
    int grp  = threadIdx.x >> 5;   // 0..7
    const float* xb = x + (size_t)b * HW_ * C_;
    float vmin = 1e30f, vmax = -1e30f;
    #pragma unroll
    for (int k = 0; k < 4; ++k) {
        int hwl = grp + 8*k;       // 0..31
        float v = xb[(size_t)(hw0 + hwl) * C_ + lane];
        tile[hwl][lane] = v;
        vmin = fminf(vmin, v); vmax = fmaxf(vmax, v);
    }
    // 64-lane wave reduce
    for (int off = 32; off; off >>= 1) {
        vmin = fminf(vmin, __shfl_down(vmin, off));
        vmax = fmaxf(vmax, __shfl_down(vmax, off));
    }
    int wave = threadIdx.x >> 6;
    if ((threadIdx.x & 63) == 0) { rmin[wave] = vmin; rmax[wave] = vmax; }
    __syncthreads();
    if (threadIdx.x == 0) {
        float m0 = fminf(fminf(rmin[0], rmin[1]), fminf(rmin[2], rmin[3]));
        float m1 = fmaxf(fmaxf(rmax[0], rmax[1]), fmaxf(rmax[2], rmax[3]));
        atomicMin(&scratch[b], enc_f32(m0));
        atomicMax(&scratch[B_ + b], enc_f32(m1));
    }
    float* xtb = xt + (size_t)b * C_ * HW_;
    #pragma unroll
    for (int k = 0; k < 4; ++k) {
        int c = grp + 8*k;
        xtb[(size_t)c * HW_ + hw0 + lane] = tile[lane][c];
    }
}

// K3: per-(b,c) plane, 32x32 output tile, quad-tree box sums in LDS.
// Window (pb,pa): r2=(0,1) r4=(1,2) r8=(3,4) r16=(7,8).
// Extents for output tile [0,32): G2 on [-7,39) (46), G4 [-6,38) (44),
// G8 [-4,36) (40), X on [-7,40) (47).
#define EXT 47
#define STR 48

__global__ __launch_bounds__(256) void k_alpha(
        const float* __restrict__ xt, float* __restrict__ at,
        const unsigned int* __restrict__ scratch) {
    __shared__ float bufA[EXT * STR];   // X, then G4
    __shared__ float bufB[46 * STR];    // G2, then G8
    int plane = blockIdx.y;             // b*32+c
    int b = plane >> 5;
    int th = blockIdx.x / 7, tw = blockIdx.x % 7;
    int h0 = th * 32, w0 = tw * 32;
    const float* P = xt + (size_t)plane * HW_;
    float mn = dec_f32(scratch[b]);
    float mx = dec_f32(scratch[B_ + b]);
    float inv = 1.0f / (mx - mn + 1e-7f);
    int tid = threadIdx.x;

    // load X ext 47x47 (zero outside plane)
    for (int i = tid; i < EXT*EXT; i += 256) {
        int r = i / EXT, cq = i - r*EXT;
        int gh = h0 - 7 + r, gw = w0 - 7 + cq;
        float v = 0.0f;
        if (gh >= 0 && gh < H_ && gw >= 0 && gw < W_) v = P[gh*W_ + gw];
        bufA[r*STR + cq] = v;
    }
    __syncthreads();
    // G2 (46x46) into bufB : rows [h,h+1] x cols [w,w+1]
    for (int i = tid; i < 46*46; i += 256) {
        int r = i / 46, cq = i - r*46;
        bufB[r*STR+cq] = bufA[r*STR+cq]     + bufA[r*STR+cq+1]
                       + bufA[(r+1)*STR+cq] + bufA[(r+1)*STR+cq+1];
    }
    __syncthreads();
    // G4 (44x44) into bufA (X dead): G2[±1]
    for (int i = tid; i < 44*44; i += 256) {
        int r = i / 44, cq = i - r*44;
        bufA[r*STR+cq] = bufB[r*STR+cq]     + bufB[r*STR+cq+2]
                       + bufB[(r+2)*STR+cq] + bufB[(r+2)*STR+cq+2];
    }
    __syncthreads();
    // save G2 at my output pixels before bufB is overwritten
    int lw = tid & 31, lh0 = tid >> 5;
    float g2r[4];
    #pragma unroll
    for (int k = 0; k < 4; ++k) {
        int lh = lh0 + 8*k;
        g2r[k] = bufB[(lh+7)*STR + (lw+7)];
    }
    __syncthreads();
    // G8 (40x40) into bufB (G2 dead): G4[±2]
    for (int i = tid; i < 40*40; i += 256) {
        int r = i / 40, cq = i - r*40;
        bufB[r*STR+cq] = bufA[r*STR+cq]     + bufA[r*STR+cq+4]
                       + bufA[(r+4)*STR+cq] + bufA[(r+4)*STR+cq+4];
    }
    __syncthreads();

    float* Q = at + (size_t)plane * HW_;
    #pragma unroll
    for (int k = 0; k < 4; ++k) {
        int lh = lh0 + 8*k;
        int gh = h0 + lh, gw = w0 + lw;
        float g2 = g2r[k];
        float g4 = bufA[(lh+6)*STR + (lw+6)];
        float g8 = bufB[(lh+4)*STR + (lw+4)];
        float g16 = bufB[lh*STR + lw]       + bufB[lh*STR + lw+8]
                  + bufB[(lh+8)*STR + lw]   + bufB[(lh+8)*STR + lw+8];
        // analytic valid-pixel counts (zero-padded SAME windows)
        int ch2  = min(gh+1, H_-1) - gh + 1;
        int cw2  = min(gw+1, W_-1) - gw + 1;
        int ch4  = min(gh+2, H_-1) - max(gh-1, 0) + 1;
        int cw4  = min(gw+2, W_-1) - max(gw-1, 0) + 1;
        int ch8  = min(gh+4, H_-1) - max(gh-3, 0) + 1;
        int cw8  = min(gw+4, W_-1) - max(gw-3, 0) + 1;
        int ch16 = min(gh+8, H_-1) - max(gh-7, 0) + 1;
        int cw16 = min(gw+8, W_-1) - max(gw-7, 0) + 1;
        float m2  = fmaxf((g2  - mn*(float)(ch2 *cw2 )) * inv, 0.0f);
        float m4  = fmaxf((g4  - mn*(float)(ch4 *cw4 )) * inv, 0.0f);
        float m8  = fmaxf((g8  - mn*(float)(ch8 *cw8 )) * inv, 0.0f);
        float m16 = fmaxf((g16 - mn*(float)(ch16*cw16)) * inv, 0.0f);
        float L1 = __logf(m2  + 1e-7f);
        float L2 = __logf(m4  + 1e-7f);
        float L3 = __logf(m8  + 1e-7f);
        float L4 = __logf(m16 + 1e-7f);
        // alpha = sum(ls_c * L)/sum(ls_c^2), ls_c = ln2*{-1.5,-0.5,0.5,1.5}
        float alpha = (1.5f*(L4 - L1) + 0.5f*(L3 - L2)) * (1.0f/(5.0f*0.693147180559945f));
        Q[gh*W_ + gw] = alpha;
    }
}

// K4: NCHW alpha -> NHWC out with BatchNorm (inference)
__global__ __launch_bounds__(256) void k_out(
        const float* __restrict__ at,
        const float* __restrict__ gamma, const float* __restrict__ beta,
        const float* __restrict__ mmean, const float* __restrict__ mvar,
        float* __restrict__ out) {
    __shared__ float tile[32][33];
    int b = blockIdx.y;
    int hw0 = blockIdx.x * 32;
    int lane = threadIdx.x & 31;
    int grp  = threadIdx.x >> 5;
    const float* ab = at + (size_t)b * C_ * HW_;
    #pragma unroll
    for (int k = 0; k < 4; ++k) {
        int c = grp + 8*k;
        tile[lane][c] = ab[(size_t)c * HW_ + hw0 + lane];
    }
    __syncthreads();
    int c_out = lane;
    float scale = gamma[c_out] * rsqrtf(mvar[c_out] + 1e-3f);
    float mu = mmean[c_out], be = beta[c_out];
    float* ob = out + (size_t)b * HW_ * C_;
    #pragma unroll
    for (int k = 0; k < 4; ++k) {
        int hwl = grp + 8*k;
        ob[(size_t)(hw0 + hwl) * C_ + c_out] = (tile[hwl][c_out] - mu) * scale + be;
    }
}

extern "C" void kernel_launch(void* const* d_in, const int* in_sizes, int n_in,
                              void* d_out, int out_size, void* d_ws, size_t ws_size,
                              hipStream_t stream) {
    const float* x     = (const float*)d_in[0];
    const float* gamma = (const float*)d_in[1];
    const float* beta  = (const float*)d_in[2];
    const float* mmean = (const float*)d_in[3];
    const float* mvar  = (const float*)d_in[4];
    float* out = (float*)d_out;

    float* xt = (float*)d_ws;                 // NCHW staging, NTOT_ floats
    float* at = xt + NTOT_;                   // NCHW alphas,  NTOT_ floats
    unsigned int* scratch = (unsigned int*)(at + NTOT_);  // 32 uints

    k_init<<<1, 64, 0, stream>>>(scratch);
    dim3 g1(HW_/32, B_);
    k_transpose_minmax<<<g1, 256, 0, stream>>>(x, xt, scratch);
    dim3 g3(49, B_*C_);
    k_alpha<<<g3, 256, 0, stream>>>(xt, at, scratch);
    k_out<<<g1, 256, 0, stream>>>(at, gamma, beta, mmean, mvar, out);
}

// Round 2
// 380.758 us; speedup vs baseline: 1.5936x; 1.5936x over previous
//
#include <hip/hip_runtime.h>
#include <cstdint>

#define B_ 16
#define H_ 224
#define W_ 224
#define C_ 32
#define HW_ (H_*W_)            // 50176
#define NTOT_ ((size_t)B_*HW_*C_)
#define TILES_PER_B (HW_/32)   // 1568

__device__ __forceinline__ unsigned int enc_f32(float f) {
    unsigned int u = __float_as_uint(f);
    return (u & 0x80000000u) ? ~u : (u | 0x80000000u);
}
__device__ __forceinline__ float dec_f32(unsigned int u) {
    unsigned int v = (u & 0x80000000u) ? (u & 0x7fffffffu) : ~u;
    return __uint_as_float(v);
}

__global__ void k_init(unsigned int* scratch) {
    int t = threadIdx.x;
    if (t < B_) { scratch[t] = 0xFFFFFFFFu; scratch[B_ + t] = 0u; }
}

// K1: NHWC -> NCHW transpose + per-sample min/max.
// grid (128, B_): blockIdx.y = sample; grid-stride over that sample's 32-pixel
// tiles. Each [32 hw][32 c] tile is a CONTIGUOUS 4KB chunk of x -> float4
// stream in, LDS transpose, float4 stream out. ONE atomic pair per block
// (4096 total, 128/address) instead of one per tile (50k -> was the 293us
// serialization bottleneck in R1).
__global__ __launch_bounds__(256) void k_transpose_minmax(
        const float* __restrict__ x, float* __restrict__ xt,
        unsigned int* __restrict__ scratch) {
    __shared__ float tile[32][33];
    __shared__ float rmin[4], rmax[4];
    int t = threadIdx.x;
    int b = blockIdx.y;
    const float4* xb4 = (const float4*)(x + (size_t)b * HW_ * C_);
    float* xtb = xt + (size_t)b * C_ * HW_;
    float vmin = 1e30f, vmax = -1e30f;
    int lrow = t >> 3, lc4 = (t & 7) * 4;   // load mapping
    int wc = t >> 3, ww4 = (t & 7) * 4;     // write mapping

    for (int tile_i = blockIdx.x; tile_i < TILES_PER_B; tile_i += gridDim.x) {
        int hw0 = tile_i * 32;
        float4 v = xb4[(size_t)hw0 * C_ / 4 + t];   // contiguous 4KB
        vmin = fminf(vmin, fminf(fminf(v.x, v.y), fminf(v.z, v.w)));
        vmax = fmaxf(vmax, fmaxf(fmaxf(v.x, v.y), fmaxf(v.z, v.w)));
        tile[lrow][lc4+0] = v.x; tile[lrow][lc4+1] = v.y;
        tile[lrow][lc4+2] = v.z; tile[lrow][lc4+3] = v.w;
        __syncthreads();
        float4 o;
        o.x = tile[ww4+0][wc]; o.y = tile[ww4+1][wc];
        o.z = tile[ww4+2][wc]; o.w = tile[ww4+3][wc];
        *(float4*)(xtb + (size_t)wc * HW_ + hw0 + ww4) = o;
        __syncthreads();
    }
    // block-level min/max reduce -> single atomic pair
    for (int off = 32; off; off >>= 1) {
        vmin = fminf(vmin, __shfl_down(vmin, off));
        vmax = fmaxf(vmax, __shfl_down(vmax, off));
    }
    int wave = t >> 6;
    if ((t & 63) == 0) { rmin[wave] = vmin; rmax[wave] = vmax; }
    __syncthreads();
    if (t == 0) {
        float m0 = fminf(fminf(rmin[0], rmin[1]), fminf(rmin[2], rmin[3]));
        float m1 = fmaxf(fmaxf(rmax[0], rmax[1]), fmaxf(rmax[2], rmax[3]));
        atomicMin(&scratch[b], enc_f32(m0));
        atomicMax(&scratch[B_ + b], enc_f32(m1));
    }
}

// K3: per-(b,c) plane, 56x56 output tile (224 = 4x56, zero waste),
// quad-tree box sums in LDS. Windows (rel. offsets, zero-padded SAME):
//   G2[h]=X[h]+X[h+1]; G4[h]=G2[h-1]+G2[h+1]; G8[h]=G4[h-2]+G4[h+2];
//   G16[h]=G8[h-4]+G8[h+4]   (each applied in both dims)
// Extents: X 71(base -7), G2 70(-7), G4 68(-6), G8 64(-4). LDS 40.6 KB.
#define T_ 56
#define XE 71
#define G2E 70
#define G4E 68
#define G8E 64
#define STR 72

__global__ __launch_bounds__(512) void k_alpha(
        const float* __restrict__ xt, float* __restrict__ at,
        const unsigned int* __restrict__ scratch) {
    __shared__ float bufA[XE * STR];    // X, then G4
    __shared__ float bufB[G2E * STR];   // G2, then G8
    int plane = blockIdx.y;             // b*32+c
    int b = plane >> 5;
    int th = blockIdx.x >> 2, tw = blockIdx.x & 3;
    int h0 = th * T_, w0 = tw * T_;
    const float* P = xt + (size_t)plane * HW_;
    float mn = dec_f32(scratch[b]);
    float mx = dec_f32(scratch[B_ + b]);
    float inv = 1.0f / (mx - mn + 1e-7f);
    int tid = threadIdx.x;

    // load X ext 71x71 (zero outside plane)
    for (int i = tid; i < XE*XE; i += 512) {
        int r = i / XE, cq = i - r*XE;
        int gh = h0 - 7 + r, gw = w0 - 7 + cq;
        float v = 0.0f;
        if (gh >= 0 && gh < H_ && gw >= 0 && gw < W_) v = P[gh*W_ + gw];
        bufA[r*STR + cq] = v;
    }
    __syncthreads();
    // G2 (70x70) into bufB
    for (int i = tid; i < G2E*G2E; i += 512) {
        int r = i / G2E, cq = i - r*G2E;
        bufB[r*STR+cq] = bufA[r*STR+cq]     + bufA[r*STR+cq+1]
                       + bufA[(r+1)*STR+cq] + bufA[(r+1)*STR+cq+1];
    }
    __syncthreads();
    // G4 (68x68) into bufA (X dead)
    for (int i = tid; i < G4E*G4E; i += 512) {
        int r = i / G4E, cq = i - r*G4E;
        bufA[r*STR+cq] = bufB[r*STR+cq]     + bufB[r*STR+cq+2]
                       + bufB[(r+2)*STR+cq] + bufB[(r+2)*STR+cq+2];
    }
    __syncthreads();
    // save G2 at my output pixels before bufB is overwritten
    float g2r[7];
    #pragma unroll
    for (int k = 0; k < 7; ++k) {
        int i = tid + 512*k;
        if (i < T_*T_) {
            int lh = i / T_, lw = i - lh*T_;
            g2r[k] = bufB[(lh+7)*STR + (lw+7)];
        }
    }
    __syncthreads();
    // G8 (64x64) into bufB (G2 dead)
    for (int i = tid; i < G8E*G8E; i += 512) {
        int r = i / G8E, cq = i - r*G8E;
        bufB[r*STR+cq] = bufA[r*STR+cq]     + bufA[r*STR+cq+4]
                       + bufA[(r+4)*STR+cq] + bufA[(r+4)*STR+cq+4];
    }
    __syncthreads();

    float* Q = at + (size_t)plane * HW_;
    #pragma unroll
    for (int k = 0; k < 7; ++k) {
        int i = tid + 512*k;
        if (i >= T_*T_) break;
        int lh = i / T_, lw = i - lh*T_;
        int gh = h0 + lh, gw = w0 + lw;
        float g2 = g2r[k];
        float g4 = bufA[(lh+6)*STR + (lw+6)];
        float g8 = bufB[(lh+4)*STR + (lw+4)];
        float g16 = bufB[lh*STR + lw]       + bufB[lh*STR + lw+8]
                  + bufB[(lh+8)*STR + lw]   + bufB[(lh+8)*STR + lw+8];
        // analytic valid-pixel counts (zero-padded SAME windows)
        int ch2  = min(gh+1, H_-1) - gh + 1;
        int cw2  = min(gw+1, W_-1) - gw + 1;
        int ch4  = min(gh+2, H_-1) - max(gh-1, 0) + 1;
        int cw4  = min(gw+2, W_-1) - max(gw-1, 0) + 1;
        int ch8  = min(gh+4, H_-1) - max(gh-3, 0) + 1;
        int cw8  = min(gw+4, W_-1) - max(gw-3, 0) + 1;
        int ch16 = min(gh+8, H_-1) - max(gh-7, 0) + 1;
        int cw16 = min(gw+8, W_-1) - max(gw-7, 0) + 1;
        float m2  = fmaxf((g2  - mn*(float)(ch2 *cw2 )) * inv, 0.0f);
        float m4  = fmaxf((g4  - mn*(float)(ch4 *cw4 )) * inv, 0.0f);
        float m8  = fmaxf((g8  - mn*(float)(ch8 *cw8 )) * inv, 0.0f);
        float m16 = fmaxf((g16 - mn*(float)(ch16*cw16)) * inv, 0.0f);
        float L1 = __logf(m2  + 1e-7f);
        float L2 = __logf(m4  + 1e-7f);
        float L3 = __logf(m8  + 1e-7f);
        float L4 = __logf(m16 + 1e-7f);
        float alpha = (1.5f*(L4 - L1) + 0.5f*(L3 - L2)) * (1.0f/(5.0f*0.693147180559945f));
        Q[gh*W_ + gw] = alpha;
    }
}

// K4: NCHW alpha -> NHWC out with BatchNorm. Same float4-through-LDS scheme
// as K1 but reversed; grid-stride over all 25088 tiles.
__global__ __launch_bounds__(256) void k_out(
        const float* __restrict__ at,
        const float* __restrict__ gamma, const float* __restrict__ beta,
        const float* __restrict__ mmean, const float* __restrict__ mvar,
        float* __restrict__ out) {
    __shared__ float tile[32][33];
    __shared__ float s_scale[32], s_bias[32];
    int t = threadIdx.x;
    if (t < 32) {
        float sc = gamma[t] * rsqrtf(mvar[t] + 1e-3f);
        s_scale[t] = sc;
        s_bias[t]  = beta[t] - mmean[t] * sc;
    }
    __syncthreads();
    int rc = t >> 3, rw4 = (t & 7) * 4;   // read: c-plane row chunk
    int wrow = t >> 3, wc4 = (t & 7) * 4; // write: NHWC chunk

    for (int tidx = blockIdx.x; tidx < B_ * TILES_PER_B; tidx += gridDim.x) {
        int b = tidx / TILES_PER_B;
        int hw0 = (tidx - b * TILES_PER_B) * 32;
        const float* ab = at + (size_t)b * C_ * HW_;
        float4 v = *(const float4*)(ab + (size_t)rc * HW_ + hw0 + rw4);
        tile[rw4+0][rc] = v.x; tile[rw4+1][rc] = v.y;
        tile[rw4+2][rc] = v.z; tile[rw4+3][rc] = v.w;
        __syncthreads();
        float4 o;
        o.x = tile[wrow][wc4+0] * s_scale[wc4+0] + s_bias[wc4+0];
        o.y = tile[wrow][wc4+1] * s_scale[wc4+1] + s_bias[wc4+1];
        o.z = tile[wrow][wc4+2] * s_scale[wc4+2] + s_bias[wc4+2];
        o.w = tile[wrow][wc4+3] * s_scale[wc4+3] + s_bias[wc4+3];
        *(float4*)(out + ((size_t)b * HW_ + hw0 + wrow) * C_ + wc4) = o;
        __syncthreads();
    }
}

extern "C" void kernel_launch(void* const* d_in, const int* in_sizes, int n_in,
                              void* d_out, int out_size, void* d_ws, size_t ws_size,
                              hipStream_t stream) {
    const float* x     = (const float*)d_in[0];
    const float* gamma = (const float*)d_in[1];
    const float* beta  = (const float*)d_in[2];
    const float* mmean = (const float*)d_in[3];
    const float* mvar  = (const float*)d_in[4];
    float* out = (float*)d_out;

    float* xt = (float*)d_ws;                 // NCHW staging, NTOT_ floats
    float* at = xt + NTOT_;                   // NCHW alphas,  NTOT_ floats
    unsigned int* scratch = (unsigned int*)(at + NTOT_);  // 32 uints

    k_init<<<1, 64, 0, stream>>>(scratch);
    k_transpose_minmax<<<dim3(128, B_), 256, 0, stream>>>(x, xt, scratch);
    k_alpha<<<dim3(16, B_*C_), 512, 0, stream>>>(xt, at, scratch);
    k_out<<<2048, 256, 0, stream>>>(at, gamma, beta, mmean, mvar, out);
}

// Round 3
// 372.582 us; speedup vs baseline: 1.6285x; 1.0219x over previous
//
#include <hip/hip_runtime.h>
#include <cstdint>

#define B_ 16
#define H_ 224
#define W_ 224
#define C_ 32
#define HW_ (H_*W_)            // 50176
#define NTOT_ ((size_t)B_*HW_*C_)
#define TILES_PER_B (HW_/32)   // 1568

__device__ __forceinline__ unsigned int enc_f32(float f) {
    unsigned int u = __float_as_uint(f);
    return (u & 0x80000000u) ? ~u : (u | 0x80000000u);
}
__device__ __forceinline__ float dec_f32(unsigned int u) {
    unsigned int v = (u & 0x80000000u) ? (u & 0x7fffffffu) : ~u;
    return __uint_as_float(v);
}

__global__ void k_init(unsigned int* scratch) {
    int t = threadIdx.x;
    if (t < B_) { scratch[t] = 0xFFFFFFFFu; scratch[B_ + t] = 0u; }
}

// K1: NHWC -> NCHW transpose + per-sample min/max (1 atomic pair per block).
__global__ __launch_bounds__(256) void k_transpose_minmax(
        const float* __restrict__ x, float* __restrict__ xt,
        unsigned int* __restrict__ scratch) {
    __shared__ float tile[32][33];
    __shared__ float rmin[4], rmax[4];
    int t = threadIdx.x;
    int b = blockIdx.y;
    const float4* xb4 = (const float4*)(x + (size_t)b * HW_ * C_);
    float* xtb = xt + (size_t)b * C_ * HW_;
    float vmin = 1e30f, vmax = -1e30f;
    int lrow = t >> 3, lc4 = (t & 7) * 4;
    int wc = t >> 3, ww4 = (t & 7) * 4;

    for (int tile_i = blockIdx.x; tile_i < TILES_PER_B; tile_i += gridDim.x) {
        int hw0 = tile_i * 32;
        float4 v = xb4[(size_t)hw0 * C_ / 4 + t];
        vmin = fminf(vmin, fminf(fminf(v.x, v.y), fminf(v.z, v.w)));
        vmax = fmaxf(vmax, fmaxf(fmaxf(v.x, v.y), fmaxf(v.z, v.w)));
        tile[lrow][lc4+0] = v.x; tile[lrow][lc4+1] = v.y;
        tile[lrow][lc4+2] = v.z; tile[lrow][lc4+3] = v.w;
        __syncthreads();
        float4 o;
        o.x = tile[ww4+0][wc]; o.y = tile[ww4+1][wc];
        o.z = tile[ww4+2][wc]; o.w = tile[ww4+3][wc];
        *(float4*)(xtb + (size_t)wc * HW_ + hw0 + ww4) = o;
        __syncthreads();
    }
    for (int off = 32; off; off >>= 1) {
        vmin = fminf(vmin, __shfl_down(vmin, off));
        vmax = fmaxf(vmax, __shfl_down(vmax, off));
    }
    int wave = t >> 6;
    if ((t & 63) == 0) { rmin[wave] = vmin; rmax[wave] = vmax; }
    __syncthreads();
    if (t == 0) {
        float m0 = fminf(fminf(rmin[0], rmin[1]), fminf(rmin[2], rmin[3]));
        float m1 = fmaxf(fmaxf(rmax[0], rmax[1]), fmaxf(rmax[2], rmax[3]));
        atomicMin(&scratch[b], enc_f32(m0));
        atomicMax(&scratch[B_ + b], enc_f32(m1));
    }
}

// K3 v3: wave-autonomous, zero LDS. Lane = one column; 28-row output band in
// registers. Separable tree: V-passes = register adds; H-passes = 1 shfl_down
// per row per level (left-aligned frames, spans 1/2/4/8); realign consumed
// levels with shfl_up 1/3/7. Wave covers 64 cols ext = 49 output cols.
// Per plane: 5 col-tiles x 8 row-bands (224 = 8*28). Was: LDS quad-tree at
// VALUBusy 100% (index math + 5 scalar LDS ops/elem/level) -> 152 us.
#define RB 28
#define XR (RB+15)   // 43

__global__ __launch_bounds__(256) void k_alpha(
        const float* __restrict__ xt, float* __restrict__ at,
        const unsigned int* __restrict__ scratch) {
    const int wid  = threadIdx.x >> 6;
    const int lane = threadIdx.x & 63;
    int task  = blockIdx.x * 4 + wid;          // 20480 tasks
    int plane = task / 40;                      // b*32+c
    int rem   = task - plane * 40;
    int band  = rem / 5;                        // 0..7
    int tw    = rem - band * 5;                 // 0..4
    int b     = plane >> 5;
    const float* P = xt + (size_t)plane * HW_;
    float mn  = dec_f32(scratch[b]);
    float mx  = dec_f32(scratch[B_ + b]);
    float inv = 1.0f / (mx - mn + 1e-7f);
    float minv = mn * inv;
    int w  = tw * 49 - 7 + lane;                // lane's column == its output col
    int r0 = band * RB;
    bool cok = (w >= 0 && w < W_);

    float X[XR];
    #pragma unroll
    for (int r = 0; r < XR; ++r) {
        int gh = r0 - 7 + r;
        float v = 0.0f;
        if (cok && gh >= 0 && gh < H_) v = P[gh * W_ + w];
        X[r] = v;
    }
    // level 1: H (span 1) then V -> X becomes G2 (left-aligned), rows 0..41
    #pragma unroll
    for (int r = 0; r < XR; ++r) X[r] += __shfl_down(X[r], 1);
    #pragma unroll
    for (int r = 0; r < XR-1; ++r) X[r] += X[r+1];
    // level 2: span 2 -> A4 = G4_la, rows 0..39
    float A4[XR-1];
    #pragma unroll
    for (int r = 0; r < XR-1; ++r) A4[r] = X[r] + __shfl_down(X[r], 2);
    #pragma unroll
    for (int r = 0; r < XR-3; ++r) A4[r] += A4[r+2];
    // level 3: span 4 -> A8 = G8_la, rows 0..35
    float A8[XR-3];
    #pragma unroll
    for (int r = 0; r < XR-3; ++r) A8[r] = A4[r] + __shfl_down(A4[r], 4);
    #pragma unroll
    for (int r = 0; r < XR-7; ++r) A8[r] += A8[r+4];
    // level 4: span 8 -> A16 = G16_la, rows 0..27 (== output rows)
    float A16[XR-7];
    #pragma unroll
    for (int r = 0; r < XR-7; ++r) A16[r] = A8[r] + __shfl_down(A8[r], 8);
    #pragma unroll
    for (int r = 0; r < RB; ++r) A16[r] += A16[r+8];

    // per-lane column valid-pixel counts (w>=0 for all active output lanes)
    float cw2  = (float)(min(w+1, W_-1) - w + 1);
    float cw4  = (float)(min(w+2, W_-1) - max(w-1, 0) + 1);
    float cw8  = (float)(min(w+4, W_-1) - max(w-3, 0) + 1);
    float cw16 = (float)(min(w+8, W_-1) - max(w-7, 0) + 1);
    bool outok = (lane >= 7 && lane <= 55 && w < W_);
    float* Q = at + (size_t)plane * HW_;

    #pragma unroll
    for (int lh = 0; lh < RB; ++lh) {
        int gh = r0 + lh;
        float g2  = X[lh+7];                       // G2 already col-aligned
        float g4  = __shfl_up(A4[lh+6], 1);        // realign col offset 1
        float g8  = __shfl_up(A8[lh+4], 3);        // 3
        float g16 = __shfl_up(A16[lh], 7);         // 7
        float ch2  = (float)(min(gh+1, H_-1) - gh + 1);
        float ch4  = (float)(min(gh+2, H_-1) - max(gh-1, 0) + 1);
        float ch8  = (float)(min(gh+4, H_-1) - max(gh-3, 0) + 1);
        float ch16 = (float)(min(gh+8, H_-1) - max(gh-7, 0) + 1);
        float m2  = fmaxf(fmaf(-minv, ch2 *cw2 , g2 *inv), 0.0f);
        float m4  = fmaxf(fmaf(-minv, ch4 *cw4 , g4 *inv), 0.0f);
        float m8  = fmaxf(fmaf(-minv, ch8 *cw8 , g8 *inv), 0.0f);
        float m16 = fmaxf(fmaf(-minv, ch16*cw16, g16*inv), 0.0f);
        float L1v = __logf(m2  + 1e-7f);
        float L2v = __logf(m4  + 1e-7f);
        float L3v = __logf(m8  + 1e-7f);
        float L4v = __logf(m16 + 1e-7f);
        float alpha = (1.5f*(L4v - L1v) + 0.5f*(L3v - L2v)) * 0.28853900817779268f;
        if (outok) Q[gh * W_ + w] = alpha;
    }
}

// K4: NCHW alpha -> NHWC out with BatchNorm.
__global__ __launch_bounds__(256) void k_out(
        const float* __restrict__ at,
        const float* __restrict__ gamma, const float* __restrict__ beta,
        const float* __restrict__ mmean, const float* __restrict__ mvar,
        float* __restrict__ out) {
    __shared__ float tile[32][33];
    __shared__ float s_scale[32], s_bias[32];
    int t = threadIdx.x;
    if (t < 32) {
        float sc = gamma[t] * rsqrtf(mvar[t] + 1e-3f);
        s_scale[t] = sc;
        s_bias[t]  = beta[t] - mmean[t] * sc;
    }
    __syncthreads();
    int rc = t >> 3, rw4 = (t & 7) * 4;
    int wrow = t >> 3, wc4 = (t & 7) * 4;

    for (int tidx = blockIdx.x; tidx < B_ * TILES_PER_B; tidx += gridDim.x) {
        int b = tidx / TILES_PER_B;
        int hw0 = (tidx - b * TILES_PER_B) * 32;
        const float* ab = at + (size_t)b * C_ * HW_;
        float4 v = *(const float4*)(ab + (size_t)rc * HW_ + hw0 + rw4);
        tile[rw4+0][rc] = v.x; tile[rw4+1][rc] = v.y;
        tile[rw4+2][rc] = v.z; tile[rw4+3][rc] = v.w;
        __syncthreads();
        float4 o;
        o.x = tile[wrow][wc4+0] * s_scale[wc4+0] + s_bias[wc4+0];
        o.y = tile[wrow][wc4+1] * s_scale[wc4+1] + s_bias[wc4+1];
        o.z = tile[wrow][wc4+2] * s_scale[wc4+2] + s_bias[wc4+2];
        o.w = tile[wrow][wc4+3] * s_scale[wc4+3] + s_bias[wc4+3];
        *(float4*)(out + ((size_t)b * HW_ + hw0 + wrow) * C_ + wc4) = o;
        __syncthreads();
    }
}

extern "C" void kernel_launch(void* const* d_in, const int* in_sizes, int n_in,
                              void* d_out, int out_size, void* d_ws, size_t ws_size,
                              hipStream_t stream) {
    const float* x     = (const float*)d_in[0];
    const float* gamma = (const float*)d_in[1];
    const float* beta  = (const float*)d_in[2];
    const float* mmean = (const float*)d_in[3];
    const float* mvar  = (const float*)d_in[4];
    float* out = (float*)d_out;

    float* xt = (float*)d_ws;                 // NCHW staging, NTOT_ floats
    float* at = xt + NTOT_;                   // NCHW alphas,  NTOT_ floats
    unsigned int* scratch = (unsigned int*)(at + NTOT_);  // 32 uints

    k_init<<<1, 64, 0, stream>>>(scratch);
    k_transpose_minmax<<<dim3(128, B_), 256, 0, stream>>>(x, xt, scratch);
    k_alpha<<<5120, 256, 0, stream>>>(xt, at, scratch);   // 20480 wave-tasks
    k_out<<<2048, 256, 0, stream>>>(at, gamma, beta, mmean, mvar, out);
}

// Round 4
// 327.469 us; speedup vs baseline: 1.8529x; 1.1378x over previous
//
#include <hip/hip_runtime.h>
#include <cstdint>

#define B_ 16
#define H_ 224
#define W_ 224
#define C_ 32
#define HW_ (H_*W_)            // 50176
#define NTOT_ ((size_t)B_*HW_*C_)
#define TILES_PER_B (HW_/32)   // 1568

__device__ __forceinline__ unsigned int enc_f32(float f) {
    unsigned int u = __float_as_uint(f);
    return (u & 0x80000000u) ? ~u : (u | 0x80000000u);
}
__device__ __forceinline__ float dec_f32(unsigned int u) {
    unsigned int v = (u & 0x80000000u) ? (u & 0x7fffffffu) : ~u;
    return __uint_as_float(v);
}

__global__ void k_init(unsigned int* scratch) {
    int t = threadIdx.x;
    if (t < B_) { scratch[t] = 0xFFFFFFFFu; scratch[B_ + t] = 0u; }
}

// K1: NHWC -> NCHW transpose + per-sample min/max (1 atomic pair per block).
// (unchanged from R3 for clean attribution of the remaining ~230us)
__global__ __launch_bounds__(256) void k_transpose_minmax(
        const float* __restrict__ x, float* __restrict__ xt,
        unsigned int* __restrict__ scratch) {
    __shared__ float tile[32][33];
    __shared__ float rmin[4], rmax[4];
    int t = threadIdx.x;
    int b = blockIdx.y;
    const float4* xb4 = (const float4*)(x + (size_t)b * HW_ * C_);
    float* xtb = xt + (size_t)b * C_ * HW_;
    float vmin = 1e30f, vmax = -1e30f;
    int lrow = t >> 3, lc4 = (t & 7) * 4;
    int wc = t >> 3, ww4 = (t & 7) * 4;

    for (int tile_i = blockIdx.x; tile_i < TILES_PER_B; tile_i += gridDim.x) {
        int hw0 = tile_i * 32;
        float4 v = xb4[(size_t)hw0 * C_ / 4 + t];
        vmin = fminf(vmin, fminf(fminf(v.x, v.y), fminf(v.z, v.w)));
        vmax = fmaxf(vmax, fmaxf(fmaxf(v.x, v.y), fmaxf(v.z, v.w)));
        tile[lrow][lc4+0] = v.x; tile[lrow][lc4+1] = v.y;
        tile[lrow][lc4+2] = v.z; tile[lrow][lc4+3] = v.w;
        __syncthreads();
        float4 o;
        o.x = tile[ww4+0][wc]; o.y = tile[ww4+1][wc];
        o.z = tile[ww4+2][wc]; o.w = tile[ww4+3][wc];
        *(float4*)(xtb + (size_t)wc * HW_ + hw0 + ww4) = o;
        __syncthreads();
    }
    for (int off = 32; off; off >>= 1) {
        vmin = fminf(vmin, __shfl_down(vmin, off));
        vmax = fmaxf(vmax, __shfl_down(vmax, off));
    }
    int wave = t >> 6;
    if ((t & 63) == 0) { rmin[wave] = vmin; rmax[wave] = vmax; }
    __syncthreads();
    if (t == 0) {
        float m0 = fminf(fminf(rmin[0], rmin[1]), fminf(rmin[2], rmin[3]));
        float m1 = fmaxf(fmaxf(rmax[0], rmax[1]), fmaxf(rmax[2], rmax[3]));
        atomicMin(&scratch[b], enc_f32(m0));
        atomicMax(&scratch[B_ + b], enc_f32(m1));
    }
}

// K3 v5: row-streaming pipeline, depth 8, zero LDS, no big register arrays
// (R3's 112-float live set spilled: WRITE_SIZE 2x, occupancy 21%).
// Lane owns a float2 column pair (cols c0=strip*112-8+2*lane, c0+1); wave
// covers 128 cols -> 112 outputs. Per iteration: ingest row a, then
//   Xh[a]       = X[a] + X[a](col+1)                (H span 1)
//   G2done[a-1] = Xh[a-1] + Xh[a]                    -> l1 for out row a-1
//   B4[a-1]     = G2done[a-1] + (col+2)   ring2 -> A4done[a-3] -> l2 (row a-2)
//   B8[a-3]     = A4done + (col+4)        ring4 -> A8done[a-7] -> l3 (row a-4)
//   B16[a-7]    = A8done + (col+8)        ring8 -> A16done[a-15]-> l4 + EMIT row a-8
// alpha = 0.3*l4 + 0.1*l3 - 0.1*l2 - 0.3*l1 (log2; OLS slope /(5 ln2) folded)
// accumulated in an 8-slot ring keyed by out-row & 7 (h0 % 8 == 0 so ring
// phases are compile-time constants under the unroll-8).
__global__ __launch_bounds__(256) void k_alpha(
        const float* __restrict__ xt, float* __restrict__ at,
        const unsigned int* __restrict__ scratch) {
    const int wid  = threadIdx.x >> 6;
    const int lane = threadIdx.x & 63;
    int task  = blockIdx.x * 4 + wid;      // 2048 tasks: plane x strip x half
    int plane = task >> 2;
    int strip = task & 1;
    int half  = (task >> 1) & 1;
    int b     = plane >> 5;
    const float* P = xt + (size_t)plane * HW_;
    float* Q = at + (size_t)plane * HW_;
    float mn  = dec_f32(scratch[b]);
    float mx  = dec_f32(scratch[B_ + b]);
    float inv = 1.0f / (mx - mn + 1e-7f);
    float minv = mn * inv;
    int sbase = strip * 112;
    int c0 = sbase - 8 + 2 * lane;
    int c1 = c0 + 1;
    int h0 = half * 112;                   // 0 or 112, both % 8 == 0
    int cl = min(max(c0, 0), W_ - 2);
    bool mC = (c0 >= 0) && (c0 <= W_ - 2); // c0 even -> c0,c1 both valid iff this
    bool laneok = (lane >= 4) && (lane <= 59);

    // per-column W-direction valid counts and folded constants
    float cw2_0  = (float)(min(c0+1, W_-1) - c0 + 1);
    float cw2_1  = (float)(min(c1+1, W_-1) - c1 + 1);
    float cw4_0  = (float)(min(c0+2, W_-1) - max(c0-1, 0) + 1);
    float cw4_1  = (float)(min(c1+2, W_-1) - max(c1-1, 0) + 1);
    float cw8_0  = (float)(min(c0+4, W_-1) - max(c0-3, 0) + 1);
    float cw8_1  = (float)(min(c1+4, W_-1) - max(c1-3, 0) + 1);
    float cw16_0 = (float)(min(c0+8, W_-1) - max(c0-7, 0) + 1);
    float cw16_1 = (float)(min(c1+8, W_-1) - max(c1-7, 0) + 1);
    float e2_0  = minv * cw2_0,  e2_1  = minv * cw2_1;
    float e4_0  = minv * cw4_0,  e4_1  = minv * cw4_1;
    float e8_0  = minv * cw8_0,  e8_1  = minv * cw8_1;
    float e16_0 = minv * cw16_0, e16_1 = minv * cw16_1;
    // interior rows: ch = 2/4/8/16 constant -> fold into additive constant
    float d2_0  = 1e-7f -  2.0f * e2_0,  d2_1  = 1e-7f -  2.0f * e2_1;
    float d4_0  = 1e-7f -  4.0f * e4_0,  d4_1  = 1e-7f -  4.0f * e4_1;
    float d8_0  = 1e-7f -  8.0f * e8_0,  d8_1  = 1e-7f -  8.0f * e8_1;
    float d16_0 = 1e-7f - 16.0f * e16_0, d16_1 = 1e-7f - 16.0f * e16_1;

    float hp0 = 0.f, hp1 = 0.f;            // Xh[a-1]
    float rB4[2][2]  = {};                 // [col][phase] delay-2
    float rB8[2][4]  = {};                 // delay-4
    float rB16[2][8] = {};                 // delay-8
    float acc[2][8]  = {};                 // alpha partials, slot = out_row & 7

    for (int it8 = 0; it8 < 16; ++it8) {
        #pragma unroll
        for (int u = 0; u < 8; ++u) {
            int it = it8 * 8 + u;
            int a = h0 - 7 + it;           // absolute input row
            float x0 = 0.f, x1 = 0.f;
            if (a >= 0 && a < H_) {        // wave-uniform branch
                float2 v = *(const float2*)(P + (size_t)a * W_ + cl);
                x0 = mC ? v.x : 0.f;
                x1 = mC ? v.y : 0.f;
            }
            // level 1 H (span 1)
            float nx0 = __shfl_down(x0, 1);
            float xh0 = x0 + x1;
            float xh1 = x1 + nx0;
            // level 1 V -> G2done[a-1] (col-aligned for out)
            float g2_0 = hp0 + xh0; hp0 = xh0;
            float g2_1 = hp1 + xh1; hp1 = xh1;
            // level 2 H (span 2 = next even/odd col)
            float b4n_0 = g2_0 + __shfl_down(g2_0, 1);
            float b4n_1 = g2_1 + __shfl_down(g2_1, 1);
            // level 2 V: A4done[a-3] = B4[a-3] + B4[a-1]
            float a4_0 = rB4[0][u & 1] + b4n_0; rB4[0][u & 1] = b4n_0;
            float a4_1 = rB4[1][u & 1] + b4n_1; rB4[1][u & 1] = b4n_1;
            // level 3 H (span 4 = 2 lanes)
            float b8n_0 = a4_0 + __shfl_down(a4_0, 2);
            float b8n_1 = a4_1 + __shfl_down(a4_1, 2);
            // level 3 V: A8done[a-7] = B8[a-7] + B8[a-3]
            float a8_0 = rB8[0][u & 3] + b8n_0; rB8[0][u & 3] = b8n_0;
            float a8_1 = rB8[1][u & 3] + b8n_1; rB8[1][u & 3] = b8n_1;
            // level 4 H (span 8 = 4 lanes)
            float b16n_0 = a8_0 + __shfl_down(a8_0, 4);
            float b16n_1 = a8_1 + __shfl_down(a8_1, 4);
            // level 4 V: A16done[a-15] = B16[a-15] + B16[a-7]
            float a16_0 = rB16[0][u] + b16n_0; rB16[0][u] = b16n_0;
            float a16_1 = rB16[1][u] + b16n_1; rB16[1][u] = b16n_1;
            // realign to output columns (window left-offsets 1/3/7)
            float g4_0  = __shfl_up(a4_1, 1);
            float g4_1  = a4_0;
            float g8_0  = __shfl_up(a8_1, 2);
            float g8_1  = __shfl_up(a8_0, 1);
            float g16_0 = __shfl_up(a16_1, 4);
            float g16_1 = __shfl_up(a16_0, 3);

            float l1_0, l1_1, l2_0, l2_1, l3_0, l3_1, l4_0, l4_1;
            if (a >= 15 && a <= 223) {     // all 4 row-counts unclamped
                l1_0 = __log2f(fmaxf(fmaf(g2_0,  inv, d2_0 ), 1e-7f));
                l1_1 = __log2f(fmaxf(fmaf(g2_1,  inv, d2_1 ), 1e-7f));
                l2_0 = __log2f(fmaxf(fmaf(g4_0,  inv, d4_0 ), 1e-7f));
                l2_1 = __log2f(fmaxf(fmaf(g4_1,  inv, d4_1 ), 1e-7f));
                l3_0 = __log2f(fmaxf(fmaf(g8_0,  inv, d8_0 ), 1e-7f));
                l3_1 = __log2f(fmaxf(fmaf(g8_1,  inv, d8_1 ), 1e-7f));
                l4_0 = __log2f(fmaxf(fmaf(g16_0, inv, d16_0), 1e-7f));
                l4_1 = __log2f(fmaxf(fmaf(g16_1, inv, d16_1), 1e-7f));
            } else {
                int o1 = a - 1, o2 = a - 2, o3 = a - 4, o4 = a - 8;
                float ch2  = (float)(min(o1+1, H_-1) - o1 + 1);
                float ch4  = (float)(min(o2+2, H_-1) - max(o2-1, 0) + 1);
                float ch8  = (float)(min(o3+4, H_-1) - max(o3-3, 0) + 1);
                float ch16 = (float)(min(o4+8, H_-1) - max(o4-7, 0) + 1);
                l1_0 = __log2f(fmaxf(fmaf(-e2_0,  ch2,  fmaf(g2_0,  inv, 1e-7f)), 1e-7f));
                l1_1 = __log2f(fmaxf(fmaf(-e2_1,  ch2,  fmaf(g2_1,  inv, 1e-7f)), 1e-7f));
                l2_0 = __log2f(fmaxf(fmaf(-e4_0,  ch4,  fmaf(g4_0,  inv, 1e-7f)), 1e-7f));
                l2_1 = __log2f(fmaxf(fmaf(-e4_1,  ch4,  fmaf(g4_1,  inv, 1e-7f)), 1e-7f));
                l3_0 = __log2f(fmaxf(fmaf(-e8_0,  ch8,  fmaf(g8_0,  inv, 1e-7f)), 1e-7f));
                l3_1 = __log2f(fmaxf(fmaf(-e8_1,  ch8,  fmaf(g8_1,  inv, 1e-7f)), 1e-7f));
                l4_0 = __log2f(fmaxf(fmaf(-e16_0, ch16, fmaf(g16_0, inv, 1e-7f)), 1e-7f));
                l4_1 = __log2f(fmaxf(fmaf(-e16_1, ch16, fmaf(g16_1, inv, 1e-7f)), 1e-7f));
            }
            // accumulate into per-out-row slots (all distinct mod 8)
            acc[0][u] = -0.3f * l1_0;                    // row a-1: init
            acc[1][u] = -0.3f * l1_1;
            acc[0][(u+7)&7] = fmaf(-0.1f, l2_0, acc[0][(u+7)&7]);  // row a-2
            acc[1][(u+7)&7] = fmaf(-0.1f, l2_1, acc[1][(u+7)&7]);
            acc[0][(u+5)&7] = fmaf( 0.1f, l3_0, acc[0][(u+5)&7]);  // row a-4
            acc[1][(u+5)&7] = fmaf( 0.1f, l3_1, acc[1][(u+5)&7]);
            int o = a - 8;                               // emit row
            if (o >= h0 && o <= h0 + 111) {              // wave-uniform
                float al0 = fmaf(0.3f, l4_0, acc[0][(u+1)&7]);
                float al1 = fmaf(0.3f, l4_1, acc[1][(u+1)&7]);
                if (laneok) {
                    float2 st; st.x = al0; st.y = al1;
                    *(float2*)(Q + (size_t)o * W_ + c0) = st;
                }
            }
        }
    }
}

// K4: NCHW alpha -> NHWC out with BatchNorm. (unchanged from R3)
__global__ __launch_bounds__(256) void k_out(
        const float* __restrict__ at,
        const float* __restrict__ gamma, const float* __restrict__ beta,
        const float* __restrict__ mmean, const float* __restrict__ mvar,
        float* __restrict__ out) {
    __shared__ float tile[32][33];
    __shared__ float s_scale[32], s_bias[32];
    int t = threadIdx.x;
    if (t < 32) {
        float sc = gamma[t] * rsqrtf(mvar[t] + 1e-3f);
        s_scale[t] = sc;
        s_bias[t]  = beta[t] - mmean[t] * sc;
    }
    __syncthreads();
    int rc = t >> 3, rw4 = (t & 7) * 4;
    int wrow = t >> 3, wc4 = (t & 7) * 4;

    for (int tidx = blockIdx.x; tidx < B_ * TILES_PER_B; tidx += gridDim.x) {
        int b = tidx / TILES_PER_B;
        int hw0 = (tidx - b * TILES_PER_B) * 32;
        const float* ab = at + (size_t)b * C_ * HW_;
        float4 v = *(const float4*)(ab + (size_t)rc * HW_ + hw0 + rw4);
        tile[rw4+0][rc] = v.x; tile[rw4+1][rc] = v.y;
        tile[rw4+2][rc] = v.z; tile[rw4+3][rc] = v.w;
        __syncthreads();
        float4 o;
        o.x = tile[wrow][wc4+0] * s_scale[wc4+0] + s_bias[wc4+0];
        o.y = tile[wrow][wc4+1] * s_scale[wc4+1] + s_bias[wc4+1];
        o.z = tile[wrow][wc4+2] * s_scale[wc4+2] + s_bias[wc4+2];
        o.w = tile[wrow][wc4+3] * s_scale[wc4+3] + s_bias[wc4+3];
        *(float4*)(out + ((size_t)b * HW_ + hw0 + wrow) * C_ + wc4) = o;
        __syncthreads();
    }
}

extern "C" void kernel_launch(void* const* d_in, const int* in_sizes, int n_in,
                              void* d_out, int out_size, void* d_ws, size_t ws_size,
                              hipStream_t stream) {
    const float* x     = (const float*)d_in[0];
    const float* gamma = (const float*)d_in[1];
    const float* beta  = (const float*)d_in[2];
    const float* mmean = (const float*)d_in[3];
    const float* mvar  = (const float*)d_in[4];
    float* out = (float*)d_out;

    float* xt = (float*)d_ws;                 // NCHW staging, NTOT_ floats
    float* at = xt + NTOT_;                   // NCHW alphas,  NTOT_ floats
    unsigned int* scratch = (unsigned int*)(at + NTOT_);  // 32 uints

    k_init<<<1, 64, 0, stream>>>(scratch);
    k_transpose_minmax<<<dim3(128, B_), 256, 0, stream>>>(x, xt, scratch);
    k_alpha<<<512, 256, 0, stream>>>(xt, at, scratch);    // 2048 wave-tasks
    k_out<<<2048, 256, 0, stream>>>(at, gamma, beta, mmean, mvar, out);
}